// Round 3
// baseline (1214.781 us; speedup 1.0000x reference)
//
#include <hip/hip_runtime.h>
#include <hip/hip_bf16.h>

#define S_LEN 2048
#define E_DIM 1024
#define D_DIM 1024

typedef __bf16 bf16x8 __attribute__((ext_vector_type(8)));
typedef __bf16 bf16x4 __attribute__((ext_vector_type(4)));
typedef float f32x4 __attribute__((ext_vector_type(4)));

__device__ __forceinline__ __bf16 f2bf(float f) {
    unsigned u = __builtin_bit_cast(unsigned, f);
    u += 0x7fffu + ((u >> 16) & 1u);
    unsigned short h = (unsigned short)(u >> 16);
    return __builtin_bit_cast(__bf16, h);
}

// XOR swizzle: rows are 128 B; toggle bits 4-6 by row&7 to spread banks.
__device__ __forceinline__ int swz(int row, int byte_in_row) {
    return row * 128 + (byte_in_row ^ ((row & 7) << 4));
}

#define MFMA_BLOCK()                                                              \
    _Pragma("unroll")                                                             \
    for (int kk = 0; kk < 2; ++kk) {                                              \
        const int kb = kk * 64 + lh * 16;                                         \
        bf16x8 a[4], b[4];                                                        \
        _Pragma("unroll")                                                         \
        for (int m = 0; m < 4; ++m)                                               \
            a[m] = *reinterpret_cast<const bf16x8*>(lsA + swz(wr*64 + m*16 + rl, kb)); \
        _Pragma("unroll")                                                         \
        for (int n = 0; n < 4; ++n)                                               \
            b[n] = *reinterpret_cast<const bf16x8*>(lsB + swz(wc*64 + n*16 + rl, kb)); \
        _Pragma("unroll")                                                         \
        for (int m = 0; m < 4; ++m)                                               \
            _Pragma("unroll")                                                     \
            for (int n = 0; n < 4; ++n)                                           \
                acc[m][n] = __builtin_amdgcn_mfma_f32_16x16x32_bf16(a[m], b[n], acc[m][n], 0, 0, 0); \
    }

// ---------------- K1: QKV projection (f32 in, bf16 out; V transposed) --------
__global__ __launch_bounds__(256) void qkv_kernel(
    const float* __restrict__ X,
    const float* __restrict__ Wq, const float* __restrict__ Wk, const float* __restrict__ Wv,
    __bf16* __restrict__ Qb, __bf16* __restrict__ Kb, __bf16* __restrict__ Vt)
{
    __shared__ __align__(16) char lsA[128 * 128];
    __shared__ __align__(16) char lsB[128 * 128];

    const int nt = blockIdx.x, mt = blockIdx.y, z = blockIdx.z;
    const float* W = (z == 0) ? Wq : (z == 1) ? Wk : Wv;
    const int m0 = mt * 128, n0 = nt * 128;
    const int tid = threadIdx.x, lane = tid & 63, wid = tid >> 6;
    const int wr = wid >> 1, wc = wid & 1;
    const int rl = lane & 15, lh = lane >> 4;

    f32x4 acc[4][4] = {};

    const int arb = tid >> 4, ac = (tid & 15) * 4;
    const int bkb = tid >> 5, bc = (tid & 31) * 4;

    for (int k0 = 0; k0 < E_DIM; k0 += 64) {
        #pragma unroll
        for (int p = 0; p < 8; ++p) {           // A tile 128x64 f32 -> bf16
            int r = p * 16 + arb;
            float4 v = *reinterpret_cast<const float4*>(X + (size_t)(m0 + r) * E_DIM + k0 + ac);
            bf16x4 h = { f2bf(v.x), f2bf(v.y), f2bf(v.z), f2bf(v.w) };
            *reinterpret_cast<bf16x4*>(lsA + swz(r, ac * 2)) = h;
        }
        #pragma unroll
        for (int p = 0; p < 8; ++p) {           // B tile 64x128 transposed into lsB[n][k]
            int kr = p * 8 + bkb;
            float4 v = *reinterpret_cast<const float4*>(W + (size_t)(k0 + kr) * D_DIM + n0 + bc);
            *reinterpret_cast<__bf16*>(lsB + swz(bc + 0, kr * 2)) = f2bf(v.x);
            *reinterpret_cast<__bf16*>(lsB + swz(bc + 1, kr * 2)) = f2bf(v.y);
            *reinterpret_cast<__bf16*>(lsB + swz(bc + 2, kr * 2)) = f2bf(v.z);
            *reinterpret_cast<__bf16*>(lsB + swz(bc + 3, kr * 2)) = f2bf(v.w);
        }
        __syncthreads();
        MFMA_BLOCK()
        __syncthreads();
    }

    if (z < 2) {
        __bf16* O = (z == 0) ? Qb : Kb;
        #pragma unroll
        for (int m = 0; m < 4; ++m) {
            int row = m0 + wr*64 + m*16 + lh*4;
            #pragma unroll
            for (int n = 0; n < 4; ++n) {
                int col = n0 + wc*64 + n*16 + rl;
                #pragma unroll
                for (int r = 0; r < 4; ++r)
                    O[(size_t)(row + r) * D_DIM + col] = f2bf(acc[m][n][r]);
            }
        }
    } else {
        const int bz = m0 >> 11;        // which batch
        const int srow = m0 & 2047;
        __bf16* O = Vt + (size_t)bz * D_DIM * S_LEN;
        #pragma unroll
        for (int m = 0; m < 4; ++m) {
            int row = srow + wr*64 + m*16 + lh*4;
            #pragma unroll
            for (int n = 0; n < 4; ++n) {
                int col = n0 + wc*64 + n*16 + rl;
                bf16x4 h = { f2bf(acc[m][n][0]), f2bf(acc[m][n][1]),
                             f2bf(acc[m][n][2]), f2bf(acc[m][n][3]) };
                *reinterpret_cast<bf16x4*>(O + (size_t)col * S_LEN + row) = h;
            }
        }
    }
}

// ---------------- K2: scores = QK^T/32, P = mask*exp(s), rowsums -------------
__global__ __launch_bounds__(256) void qk_kernel(
    const __bf16* __restrict__ Qb, const __bf16* __restrict__ Kb,
    const int* __restrict__ mask, __bf16* __restrict__ P, float* __restrict__ rowsum)
{
    __shared__ __align__(16) char lsA[128 * 128];
    __shared__ __align__(16) char lsB[128 * 128];

    const int kt = blockIdx.x, qt = blockIdx.y, bz = blockIdx.z;
    const __bf16* A  = Qb + (size_t)bz * S_LEN * D_DIM;
    const __bf16* Bm = Kb + (size_t)bz * S_LEN * D_DIM;
    const int q0 = qt * 128, k0 = kt * 128;
    const int tid = threadIdx.x, lane = tid & 63, wid = tid >> 6;
    const int wr = wid >> 1, wc = wid & 1;
    const int rl = lane & 15, lh = lane >> 4;

    f32x4 acc[4][4] = {};
    const int srb = tid >> 3, sc = (tid & 7) * 8;

    for (int d0 = 0; d0 < D_DIM; d0 += 64) {
        #pragma unroll
        for (int p = 0; p < 4; ++p) {
            int r = p * 32 + srb;
            int4 va = *reinterpret_cast<const int4*>(A  + (size_t)(q0 + r) * D_DIM + d0 + sc);
            *reinterpret_cast<int4*>(lsA + swz(r, sc * 2)) = va;
            int4 vb = *reinterpret_cast<const int4*>(Bm + (size_t)(k0 + r) * D_DIM + d0 + sc);
            *reinterpret_cast<int4*>(lsB + swz(r, sc * 2)) = vb;
        }
        __syncthreads();
        MFMA_BLOCK()
        __syncthreads();
    }

    float rs[4][4] = {};
    const size_t mbase = (size_t)bz * S_LEN * S_LEN;
    #pragma unroll
    for (int m = 0; m < 4; ++m) {
        int row = q0 + wr*64 + m*16 + lh*4;
        #pragma unroll
        for (int n = 0; n < 4; ++n) {
            int col = k0 + wc*64 + n*16 + rl;
            #pragma unroll
            for (int r = 0; r < 4; ++r) {
                float s = acc[m][n][r] * 0.03125f;
                int mk = mask[mbase + (size_t)(row + r) * S_LEN + col];
                float pv = mk ? __expf(s) : 0.0f;
                rs[m][r] += pv;
                P[mbase + (size_t)(row + r) * S_LEN + col] = f2bf(pv);
            }
        }
    }
    #pragma unroll
    for (int m = 0; m < 4; ++m) {
        #pragma unroll
        for (int r = 0; r < 4; ++r) {
            float v = rs[m][r];
            v += __shfl_xor(v, 1);
            v += __shfl_xor(v, 2);
            v += __shfl_xor(v, 4);
            v += __shfl_xor(v, 8);
            if (rl == 0)
                atomicAdd(&rowsum[bz * S_LEN + q0 + wr*64 + m*16 + lh*4 + r], v);
        }
    }
}

// ---------------- K3: out = (P @ V) / rowsum ---------------------------------
__global__ __launch_bounds__(256) void pv_kernel(
    const __bf16* __restrict__ P, const __bf16* __restrict__ Vt,
    const float* __restrict__ rowsum, float* __restrict__ out)
{
    __shared__ __align__(16) char lsA[128 * 128];
    __shared__ __align__(16) char lsB[128 * 128];

    const int dt = blockIdx.x, qt = blockIdx.y, bz = blockIdx.z;
    const __bf16* A  = P  + (size_t)bz * S_LEN * S_LEN;   // [2048][2048]
    const __bf16* Bv = Vt + (size_t)bz * D_DIM * S_LEN;   // [1024][2048]
    const int q0 = qt * 128, d0c = dt * 128;
    const int tid = threadIdx.x, lane = tid & 63, wid = tid >> 6;
    const int wr = wid >> 1, wc = wid & 1;
    const int rl = lane & 15, lh = lane >> 4;

    f32x4 acc[4][4] = {};
    const int srb = tid >> 3, sc = (tid & 7) * 8;

    for (int s0 = 0; s0 < S_LEN; s0 += 64) {
        #pragma unroll
        for (int p = 0; p < 4; ++p) {
            int r = p * 32 + srb;
            int4 va = *reinterpret_cast<const int4*>(A  + (size_t)(q0  + r) * S_LEN + s0 + sc);
            *reinterpret_cast<int4*>(lsA + swz(r, sc * 2)) = va;
            int4 vb = *reinterpret_cast<const int4*>(Bv + (size_t)(d0c + r) * S_LEN + s0 + sc);
            *reinterpret_cast<int4*>(lsB + swz(r, sc * 2)) = vb;
        }
        __syncthreads();
        MFMA_BLOCK()
        __syncthreads();
    }

    float* Ob = out + (size_t)bz * S_LEN * D_DIM;
    #pragma unroll
    for (int m = 0; m < 4; ++m) {
        int row = q0 + wr*64 + m*16 + lh*4;
        float inv[4];
        #pragma unroll
        for (int r = 0; r < 4; ++r)
            inv[r] = 1.0f / (rowsum[bz * S_LEN + row + r] + 1e-20f);
        #pragma unroll
        for (int n = 0; n < 4; ++n) {
            int col = d0c + wc*64 + n*16 + rl;
            #pragma unroll
            for (int r = 0; r < 4; ++r)
                Ob[(size_t)(row + r) * D_DIM + col] = acc[m][n][r] * inv[r];
        }
    }
}

extern "C" void kernel_launch(void* const* d_in, const int* in_sizes, int n_in,
                              void* d_out, int out_size, void* d_ws, size_t ws_size,
                              hipStream_t stream) {
    const float* x    = (const float*)d_in[0];
    const int*   mask = (const int*)  d_in[1];
    const float* Wq   = (const float*)d_in[2];
    const float* Wk   = (const float*)d_in[3];
    const float* Wv   = (const float*)d_in[4];
    float* out = (float*)d_out;

    char* ws = (char*)d_ws;
    const size_t SZ_QKV = (size_t)8 * S_LEN * D_DIM * 2;      // 32 MB each (bf16)
    const size_t SZ_P   = (size_t)8 * S_LEN * S_LEN * 2;      // 64 MB
    __bf16* Qb = (__bf16*)(ws);
    __bf16* Kb = (__bf16*)(ws + SZ_QKV);
    __bf16* Vt = (__bf16*)(ws + 2 * SZ_QKV);
    __bf16* P  = (__bf16*)(ws + 3 * SZ_QKV);
    float* rowsum = (float*)(ws + 3 * SZ_QKV + SZ_P);
    const size_t need = 3 * SZ_QKV + SZ_P + (size_t)8 * S_LEN * 4;
    if (ws_size < need) return;  // workspace too small — fail visibly, don't corrupt

    hipMemsetAsync(rowsum, 0, (size_t)8 * S_LEN * 4, stream);
    qkv_kernel<<<dim3(8, 128, 3), 256, 0, stream>>>(x, Wq, Wk, Wv, Qb, Kb, Vt);
    qk_kernel <<<dim3(16, 16, 8), 256, 0, stream>>>(Qb, Kb, mask, P, rowsum);
    pv_kernel <<<dim3(8, 16, 8),  256, 0, stream>>>(P, Vt, rowsum, out);
}

// Round 4
// 620.095 us; speedup vs baseline: 1.9590x; 1.9590x over previous
//
#include <hip/hip_runtime.h>
#include <hip/hip_bf16.h>

#define S_LEN 2048
#define E_DIM 1024
#define D_DIM 1024

typedef __bf16 bf16x8 __attribute__((ext_vector_type(8)));
typedef __bf16 bf16x4 __attribute__((ext_vector_type(4)));
typedef float f32x4 __attribute__((ext_vector_type(4)));

__device__ __forceinline__ __bf16 f2bf(float f) {
    unsigned u = __builtin_bit_cast(unsigned, f);
    u += 0x7fffu + ((u >> 16) & 1u);
    unsigned short h = (unsigned short)(u >> 16);
    return __builtin_bit_cast(__bf16, h);
}

// XOR swizzle: rows are 128 B; toggle bits 4-6 by row&7 to spread banks.
__device__ __forceinline__ int swz(int row, int byte_in_row) {
    return row * 128 + (byte_in_row ^ ((row & 7) << 4));
}

#define MFMA_BLOCK()                                                              \
    _Pragma("unroll")                                                             \
    for (int kk = 0; kk < 2; ++kk) {                                              \
        const int kb = kk * 64 + lh * 16;                                         \
        bf16x8 a[4], b[4];                                                        \
        _Pragma("unroll")                                                         \
        for (int m = 0; m < 4; ++m)                                               \
            a[m] = *reinterpret_cast<const bf16x8*>(lsA + swz(wr*64 + m*16 + rl, kb)); \
        _Pragma("unroll")                                                         \
        for (int n = 0; n < 4; ++n)                                               \
            b[n] = *reinterpret_cast<const bf16x8*>(lsB + swz(wc*64 + n*16 + rl, kb)); \
        _Pragma("unroll")                                                         \
        for (int m = 0; m < 4; ++m)                                               \
            _Pragma("unroll")                                                     \
            for (int n = 0; n < 4; ++n)                                           \
                acc[m][n] = __builtin_amdgcn_mfma_f32_16x16x32_bf16(a[m], b[n], acc[m][n], 0, 0, 0); \
    }

// ---------------- K0a: X (f32) -> Xb (bf16), flat ----------------------------
__global__ __launch_bounds__(256) void cvt_x_kernel(
    const float* __restrict__ X, __bf16* __restrict__ Xb)
{
    const int n8 = (8 * S_LEN * E_DIM) / 8;   // 2M groups of 8
    for (int i = blockIdx.x * 256 + threadIdx.x; i < n8; i += gridDim.x * 256) {
        const float* p = X + (size_t)i * 8;
        float4 a = *reinterpret_cast<const float4*>(p);
        float4 b = *reinterpret_cast<const float4*>(p + 4);
        bf16x8 h = { f2bf(a.x), f2bf(a.y), f2bf(a.z), f2bf(a.w),
                     f2bf(b.x), f2bf(b.y), f2bf(b.z), f2bf(b.w) };
        *reinterpret_cast<bf16x8*>(Xb + (size_t)i * 8) = h;
    }
}

// ---------------- K0b: W (f32 [E][D]) -> Wt (bf16 [D][E]), 3 slices ----------
__global__ __launch_bounds__(256) void wt_kernel(
    const float* __restrict__ Wq, const float* __restrict__ Wk, const float* __restrict__ Wv,
    __bf16* __restrict__ Wt)
{
    __shared__ float t[64][68];   // padded: row stride 272 B (16B-aligned, odd bank step)
    const int z = blockIdx.z;
    const float* W = (z == 0) ? Wq : (z == 1) ? Wk : Wv;
    const int d0 = blockIdx.x * 64, e0 = blockIdx.y * 64;
    const int tid = threadIdx.x;

    const int er = tid >> 4, dc = (tid & 15) * 4;
    #pragma unroll
    for (int p = 0; p < 4; ++p) {
        int e = p * 16 + er;
        float4 v = *reinterpret_cast<const float4*>(W + (size_t)(e0 + e) * D_DIM + d0 + dc);
        *reinterpret_cast<float4*>(&t[e][dc]) = v;
    }
    __syncthreads();

    const int dl = tid >> 3, ec = (tid & 7) * 8;
    __bf16* O = Wt + (size_t)z * E_DIM * D_DIM;
    #pragma unroll
    for (int p = 0; p < 2; ++p) {
        int d = p * 32 + dl;
        bf16x8 h;
        #pragma unroll
        for (int j = 0; j < 8; ++j) h[j] = f2bf(t[ec + j][d]);
        *reinterpret_cast<bf16x8*>(O + (size_t)(d0 + d) * E_DIM + e0 + ec) = h;
    }
}

// ---------------- K1: QKV projection, all-bf16 (V written transposed) --------
__global__ __launch_bounds__(256) void qkv_kernel(
    const __bf16* __restrict__ Xb, const __bf16* __restrict__ Wt,
    __bf16* __restrict__ Qb, __bf16* __restrict__ Kb, __bf16* __restrict__ Vt)
{
    __shared__ __align__(16) char lsA[128 * 128];
    __shared__ __align__(16) char lsB[128 * 128];

    const int nt = blockIdx.x, mt = blockIdx.y, z = blockIdx.z;
    const __bf16* A  = Xb;                                   // [16384][1024]
    const __bf16* Bm = Wt + (size_t)z * E_DIM * D_DIM;       // [1024][1024] d-major
    const int m0 = mt * 128, n0 = nt * 128;
    const int tid = threadIdx.x, lane = tid & 63, wid = tid >> 6;
    const int wr = wid >> 1, wc = wid & 1;
    const int rl = lane & 15, lh = lane >> 4;

    f32x4 acc[4][4] = {};
    const int srb = tid >> 3, sc = (tid & 7) * 8;

    for (int k0 = 0; k0 < E_DIM; k0 += 64) {
        #pragma unroll
        for (int p = 0; p < 4; ++p) {
            int r = p * 32 + srb;
            int4 va = *reinterpret_cast<const int4*>(A  + (size_t)(m0 + r) * E_DIM + k0 + sc);
            *reinterpret_cast<int4*>(lsA + swz(r, sc * 2)) = va;
            int4 vb = *reinterpret_cast<const int4*>(Bm + (size_t)(n0 + r) * E_DIM + k0 + sc);
            *reinterpret_cast<int4*>(lsB + swz(r, sc * 2)) = vb;
        }
        __syncthreads();
        MFMA_BLOCK()
        __syncthreads();
    }

    if (z < 2) {
        __bf16* O = (z == 0) ? Qb : Kb;
        #pragma unroll
        for (int m = 0; m < 4; ++m) {
            int row = m0 + wr*64 + m*16 + lh*4;
            #pragma unroll
            for (int n = 0; n < 4; ++n) {
                int col = n0 + wc*64 + n*16 + rl;
                #pragma unroll
                for (int r = 0; r < 4; ++r)
                    O[(size_t)(row + r) * D_DIM + col] = f2bf(acc[m][n][r]);
            }
        }
    } else {
        const int bz = m0 >> 11;        // which batch
        const int srow = m0 & 2047;
        __bf16* O = Vt + (size_t)bz * D_DIM * S_LEN;
        #pragma unroll
        for (int m = 0; m < 4; ++m) {
            int row = srow + wr*64 + m*16 + lh*4;
            #pragma unroll
            for (int n = 0; n < 4; ++n) {
                int col = n0 + wc*64 + n*16 + rl;
                bf16x4 h = { f2bf(acc[m][n][0]), f2bf(acc[m][n][1]),
                             f2bf(acc[m][n][2]), f2bf(acc[m][n][3]) };
                *reinterpret_cast<bf16x4*>(O + (size_t)col * S_LEN + row) = h;
            }
        }
    }
}

// ---------------- K2: scores = QK^T/32, P = mask*exp(s), rowsums -------------
__global__ __launch_bounds__(256) void qk_kernel(
    const __bf16* __restrict__ Qb, const __bf16* __restrict__ Kb,
    const int* __restrict__ mask, __bf16* __restrict__ P, float* __restrict__ rowsum)
{
    __shared__ __align__(16) char lsA[128 * 128];
    __shared__ __align__(16) char lsB[128 * 128];

    const int kt = blockIdx.x, qt = blockIdx.y, bz = blockIdx.z;
    const __bf16* A  = Qb + (size_t)bz * S_LEN * D_DIM;
    const __bf16* Bm = Kb + (size_t)bz * S_LEN * D_DIM;
    const int q0 = qt * 128, k0 = kt * 128;
    const int tid = threadIdx.x, lane = tid & 63, wid = tid >> 6;
    const int wr = wid >> 1, wc = wid & 1;
    const int rl = lane & 15, lh = lane >> 4;

    f32x4 acc[4][4] = {};
    const int srb = tid >> 3, sc = (tid & 7) * 8;

    for (int d0 = 0; d0 < D_DIM; d0 += 64) {
        #pragma unroll
        for (int p = 0; p < 4; ++p) {
            int r = p * 32 + srb;
            int4 va = *reinterpret_cast<const int4*>(A  + (size_t)(q0 + r) * D_DIM + d0 + sc);
            *reinterpret_cast<int4*>(lsA + swz(r, sc * 2)) = va;
            int4 vb = *reinterpret_cast<const int4*>(Bm + (size_t)(k0 + r) * D_DIM + d0 + sc);
            *reinterpret_cast<int4*>(lsB + swz(r, sc * 2)) = vb;
        }
        __syncthreads();
        MFMA_BLOCK()
        __syncthreads();
    }

    float rs[4][4] = {};
    const size_t mbase = (size_t)bz * S_LEN * S_LEN;
    #pragma unroll
    for (int m = 0; m < 4; ++m) {
        int row = q0 + wr*64 + m*16 + lh*4;
        #pragma unroll
        for (int n = 0; n < 4; ++n) {
            int col = k0 + wc*64 + n*16 + rl;
            #pragma unroll
            for (int r = 0; r < 4; ++r) {
                float s = acc[m][n][r] * 0.03125f;
                int mk = mask[mbase + (size_t)(row + r) * S_LEN + col];
                float pv = mk ? __expf(s) : 0.0f;
                rs[m][r] += pv;
                P[mbase + (size_t)(row + r) * S_LEN + col] = f2bf(pv);
            }
        }
    }
    #pragma unroll
    for (int m = 0; m < 4; ++m) {
        #pragma unroll
        for (int r = 0; r < 4; ++r) {
            float v = rs[m][r];
            v += __shfl_xor(v, 1);
            v += __shfl_xor(v, 2);
            v += __shfl_xor(v, 4);
            v += __shfl_xor(v, 8);
            if (rl == 0)
                atomicAdd(&rowsum[bz * S_LEN + q0 + wr*64 + m*16 + lh*4 + r], v);
        }
    }
}

// ---------------- K3: out = (P @ V) / rowsum ---------------------------------
__global__ __launch_bounds__(256) void pv_kernel(
    const __bf16* __restrict__ P, const __bf16* __restrict__ Vt,
    const float* __restrict__ rowsum, float* __restrict__ out)
{
    __shared__ __align__(16) char lsA[128 * 128];
    __shared__ __align__(16) char lsB[128 * 128];

    const int dt = blockIdx.x, qt = blockIdx.y, bz = blockIdx.z;
    const __bf16* A  = P  + (size_t)bz * S_LEN * S_LEN;   // [2048][2048]
    const __bf16* Bv = Vt + (size_t)bz * D_DIM * S_LEN;   // [1024][2048]
    const int q0 = qt * 128, d0c = dt * 128;
    const int tid = threadIdx.x, lane = tid & 63, wid = tid >> 6;
    const int wr = wid >> 1, wc = wid & 1;
    const int rl = lane & 15, lh = lane >> 4;

    f32x4 acc[4][4] = {};
    const int srb = tid >> 3, sc = (tid & 7) * 8;

    for (int s0 = 0; s0 < S_LEN; s0 += 64) {
        #pragma unroll
        for (int p = 0; p < 4; ++p) {
            int r = p * 32 + srb;
            int4 va = *reinterpret_cast<const int4*>(A  + (size_t)(q0  + r) * S_LEN + s0 + sc);
            *reinterpret_cast<int4*>(lsA + swz(r, sc * 2)) = va;
            int4 vb = *reinterpret_cast<const int4*>(Bv + (size_t)(d0c + r) * S_LEN + s0 + sc);
            *reinterpret_cast<int4*>(lsB + swz(r, sc * 2)) = vb;
        }
        __syncthreads();
        MFMA_BLOCK()
        __syncthreads();
    }

    float* Ob = out + (size_t)bz * S_LEN * D_DIM;
    #pragma unroll
    for (int m = 0; m < 4; ++m) {
        int row = q0 + wr*64 + m*16 + lh*4;
        float inv[4];
        #pragma unroll
        for (int r = 0; r < 4; ++r)
            inv[r] = 1.0f / (rowsum[bz * S_LEN + row + r] + 1e-20f);
        #pragma unroll
        for (int n = 0; n < 4; ++n) {
            int col = d0c + wc*64 + n*16 + rl;
            #pragma unroll
            for (int r = 0; r < 4; ++r)
                Ob[(size_t)(row + r) * D_DIM + col] = acc[m][n][r] * inv[r];
        }
    }
}

extern "C" void kernel_launch(void* const* d_in, const int* in_sizes, int n_in,
                              void* d_out, int out_size, void* d_ws, size_t ws_size,
                              hipStream_t stream) {
    const float* x    = (const float*)d_in[0];
    const int*   mask = (const int*)  d_in[1];
    const float* Wq   = (const float*)d_in[2];
    const float* Wk   = (const float*)d_in[3];
    const float* Wv   = (const float*)d_in[4];
    float* out = (float*)d_out;

    char* ws = (char*)d_ws;
    const size_t SZ_QKV = (size_t)8 * S_LEN * D_DIM * 2;      // 32 MB each (bf16)
    const size_t SZ_P   = (size_t)8 * S_LEN * S_LEN * 2;      // 64 MB
    __bf16* Qb = (__bf16*)(ws);
    __bf16* Kb = (__bf16*)(ws + SZ_QKV);
    __bf16* Vt = (__bf16*)(ws + 2 * SZ_QKV);
    char*   pbase = ws + 3 * SZ_QKV;
    __bf16* P  = (__bf16*)pbase;
    // Xb/Wt alias the P region: they are fully consumed by qkv_kernel before
    // qk_kernel writes P (stream-ordered), so this is safe and saves 38 MB.
    __bf16* Xb = (__bf16*)pbase;                              // 32 MB
    __bf16* Wt = (__bf16*)(pbase + (size_t)8 * S_LEN * E_DIM * 2);  // 6 MB
    float* rowsum = (float*)(ws + 3 * SZ_QKV + SZ_P);
    const size_t need = 3 * SZ_QKV + SZ_P + (size_t)8 * S_LEN * 4;
    if (ws_size < need) return;  // workspace too small — fail visibly, don't corrupt

    hipMemsetAsync(rowsum, 0, (size_t)8 * S_LEN * 4, stream);
    cvt_x_kernel<<<2048, 256, 0, stream>>>(x, Xb);
    wt_kernel  <<<dim3(16, 16, 3), 256, 0, stream>>>(Wq, Wk, Wv, Wt);
    qkv_kernel <<<dim3(8, 128, 3), 256, 0, stream>>>(Xb, Wt, Qb, Kb, Vt);
    qk_kernel  <<<dim3(16, 16, 8), 256, 0, stream>>>(Qb, Kb, mask, P, rowsum);
    pv_kernel  <<<dim3(8, 16, 8),  256, 0, stream>>>(P, Vt, rowsum, out);
}